// Round 4
// baseline (742.076 us; speedup 1.0000x reference)
//
#include <hip/hip_runtime.h>
#include <stdint.h>

// ---------------------------------------------------------------------------
// MiniAlignDecoder on MI355X (gfx950)  — Round 4
// R4 = R2's BK=32 GEMM K-loop (proven 187 µs; BK=64 regressed 31% in R3 —
// conflicts were hidden under the barrier drain, so the XOR swizzle bought
// nothing and the bigger staging burst cost 30%) + R3's fusions:
//  * gemm MODE 1: fused expmap0+hyperboloid epilogue writes kh directly
//  * prep kernel: transpose(w1) + w2eff + beff + lh(bf16) + cvt(e->bf16)
//  * attn: register-resident kh, XCD-aligned with gemm2's token->XCD map
//  * label_mlp: uniform operands via scalar loads
// ---------------------------------------------------------------------------

typedef unsigned short u16;
typedef __attribute__((ext_vector_type(8))) short bh8;
typedef __attribute__((ext_vector_type(4))) float f32x4;

#define DEVI static __device__ __forceinline__

DEVI float bf2f(u16 u) { return __uint_as_float(((unsigned int)u) << 16); }
DEVI u16 f2bfbits(float f) {
  unsigned int x = __float_as_uint(f);
  unsigned int r = x + 0x7fffu + ((x >> 16) & 1u);   // RNE
  return (u16)(r >> 16);
}

typedef __attribute__((address_space(1))) unsigned int gu32;
typedef __attribute__((address_space(3))) unsigned int su32;
DEVI void lds_cp16(const void* g, void* l) {
  __builtin_amdgcn_global_load_lds((gu32*)g, (su32*)l, 16, 0, 0);
}

// ---------------------------------------------------------------------------
// prep: heterogeneous roles by blockIdx.x
//  [0,512)        : w1 [1024][2048] -> w1T bf16 [2048][1024]
//  [512,640)      : w2effT[n][k] = sum_d w2[k][ch*64+d]*hyp_w[d][o], bf16 [1024][2048]
//  640            : beff[n] = b2_chunk @ hyp_w + hyp_b
//  [641,673)      : lh bf16 [65][8192] hyperboloid lift of labels
//  [673,673+8192) : e fp32 -> ebf bf16 (4 float4 per thread)
__global__ __launch_bounds__(256) void prep_kernel(
    const float* __restrict__ e, const float* __restrict__ w1,
    const float* __restrict__ w2, const float* __restrict__ b2,
    const float* __restrict__ hw, const float* __restrict__ hb,
    const float* __restrict__ label,
    u16* __restrict__ ebf, u16* __restrict__ w1T, u16* __restrict__ w2eT,
    float* __restrict__ beff, u16* __restrict__ lh) {
  __shared__ float t[64][65];
  const int blk = blockIdx.x;
  const int tid = threadIdx.x;

  if (blk >= 673) {                       // ---- cvt e -> bf16
    int base = (blk - 673) * 1024 + tid;
    const float4* in = (const float4*)e;
    ushort4* out = (ushort4*)ebf;
#pragma unroll
    for (int j = 0; j < 4; j++) {
      int i = base + j * 256;
      float4 f = in[i];
      ushort4 u;
      u.x = f2bfbits(f.x); u.y = f2bfbits(f.y); u.z = f2bfbits(f.z); u.w = f2bfbits(f.w);
      out[i] = u;
    }
  } else if (blk < 512) {                 // ---- transpose w1 -> w1T
    int c0 = (blk & 31) * 64, r0 = (blk >> 5) * 64;
    int tx = tid & 63, ty = tid >> 6;
#pragma unroll
    for (int i = 0; i < 16; i++) {
      int r = i * 4 + ty;
      t[r][tx] = w1[(size_t)(r0 + r) * 2048 + c0 + tx];
    }
    __syncthreads();
#pragma unroll
    for (int i = 0; i < 16; i++) {
      int c = i * 4 + ty;
      w1T[(size_t)(c0 + c) * 1024 + r0 + tx] = f2bfbits(t[tx][c]);
    }
  } else if (blk < 640) {                 // ---- w2eff
    int bw = blk - 512;
    int ch = bw >> 3, kb = bw & 7;
    int k = kb * 256 + tid;
    float row[64];
    const float4* rp = (const float4*)(w2 + (size_t)k * 1024 + ch * 64);
#pragma unroll
    for (int i = 0; i < 16; i++) {
      float4 f = rp[i];
      row[i * 4] = f.x; row[i * 4 + 1] = f.y; row[i * 4 + 2] = f.z; row[i * 4 + 3] = f.w;
    }
    for (int o = 0; o < 64; o++) {
      float a = 0.f;
#pragma unroll
      for (int d = 0; d < 64; d++) a = fmaf(row[d], hw[d * 64 + o], a);
      w2eT[(size_t)(ch * 64 + o) * 2048 + k] = f2bfbits(a);
    }
  } else if (blk == 640) {                // ---- beff
    for (int n = tid; n < 1024; n += 256) {
      int ch = n >> 6, o = n & 63;
      float a = hb[o];
#pragma unroll
      for (int d = 0; d < 64; d++) a += b2[ch * 64 + d] * hw[d * 64 + o];
      beff[n] = a;
    }
  } else {                                // ---- lh (bf16)
    int l = (blk - 641) * 256 + tid;
    const float4* lp = (const float4*)(label + (size_t)l * 64);
    float v[64]; float sq = 0.f;
#pragma unroll
    for (int i = 0; i < 16; i++) {
      float4 f = lp[i];
      v[i * 4] = f.x; v[i * 4 + 1] = f.y; v[i * 4 + 2] = f.z; v[i * 4 + 3] = f.w;
      sq += f.x * f.x + f.y * f.y + f.z * f.z + f.w * f.w;
    }
    float dd = fmaxf(1.f - sq, 1e-12f);
    lh[l] = f2bfbits((1.f + sq) / dd);
#pragma unroll
    for (int c = 0; c < 64; c++) lh[(size_t)(c + 1) * 8192 + l] = f2bfbits(2.f * v[c] / dd);
  }
}

// ---------------------------------------------------------------------------
// MFMA bf16 GEMM: BK=32, 128x128 tile, 4 waves (2x2), 4x4 MFMA 16x16x32/wave.
// m97/R2 structure (187 µs proven). XCD swizzle: g&7 -> XCD, each XCD gets a
// contiguous bm-range (all bn) so A-strips + full B live in its L2.
// MODE 0: relu(x+bias) -> C bf16.   MODE 1: fused expmap0 + hyperboloid
// epilogue -> kh[bh][65][1024] bf16 (wave's 64 cols = one complete head).
template <int MODE>
__global__ __launch_bounds__(256, 2) void gemm_bf16(
    const u16* __restrict__ A, const u16* __restrict__ Bt,
    const float* __restrict__ bias, u16* __restrict__ C,
    u16* __restrict__ kh, int N, int K) {
  __shared__ u16 As[128 * 32];
  __shared__ u16 Bs[128 * 32];
  const int tid = threadIdx.x;
  const int wave = tid >> 6, lane = tid & 63;
  const int fr = lane & 15, q = lane >> 4;
  const int nblk = N >> 7;
  const int g = blockIdx.x;
  const int xcd = g & 7;
  const int t = g >> 3;
  const int per = (gridDim.x >> 3) / nblk;     // bm rows per XCD
  const int bm = xcd * per + t / nblk;
  const int bn = t % nblk;
  const size_t m0 = (size_t)bm * 128;
  const int n0 = bn * 128;
  const int wm = (wave >> 1) << 6, wn = (wave & 1) << 6;
  f32x4 acc[4][4] = {};

  const int r0 = tid >> 2, o0 = (tid & 3) << 3;
  const u16* Ap0 = A + (m0 + r0) * K + o0;
  const u16* Ap1 = A + (m0 + 64 + r0) * K + o0;
  const u16* Bp0 = Bt + ((size_t)n0 + r0) * K + o0;
  const u16* Bp1 = Bt + ((size_t)n0 + 64 + r0) * K + o0;
  u16* as0 = As + wave * 512;                  // wave-uniform LDS bases
  u16* as1 = As + 2048 + wave * 512;
  u16* bs0 = Bs + wave * 512;
  u16* bs1 = Bs + 2048 + wave * 512;

  const int fq = q << 3;
  for (int kk = 0; kk < K; kk += 32) {
    lds_cp16(Ap0, as0); lds_cp16(Ap1, as1);
    lds_cp16(Bp0, bs0); lds_cp16(Bp1, bs1);
    Ap0 += 32; Ap1 += 32; Bp0 += 32; Bp1 += 32;
    __syncthreads();   // drains vmcnt(0): staged data visible
    bh8 af[4], bfr[4];
#pragma unroll
    for (int t2 = 0; t2 < 4; t2++) af[t2]  = *(const bh8*)(As + (wm + t2 * 16 + fr) * 32 + fq);
#pragma unroll
    for (int t2 = 0; t2 < 4; t2++) bfr[t2] = *(const bh8*)(Bs + (wn + t2 * 16 + fr) * 32 + fq);
#pragma unroll
    for (int i = 0; i < 4; i++)
#pragma unroll
      for (int j = 0; j < 4; j++)
        acc[i][j] = __builtin_amdgcn_mfma_f32_16x16x32_bf16(af[i], bfr[j], acc[i][j], 0, 0, 0);
    __syncthreads();   // all waves done reading before next stage overwrites
  }

  // C/D layout: col = n0+wn+j*16+fr, row = m0+wm+i*16+q*4+r  [m89-verified]
  if (MODE == 0) {
#pragma unroll
    for (int j = 0; j < 4; j++) {
      int col = n0 + wn + j * 16 + fr;
      float bv = bias[col];
#pragma unroll
      for (int i = 0; i < 4; i++) {
#pragma unroll
        for (int r = 0; r < 4; r++) {
          size_t row = m0 + wm + i * 16 + q * 4 + r;
          float v = fmaxf(acc[i][j][r] + bv, 0.f);
          C[row * N + col] = f2bfbits(v);
        }
      }
    }
  } else {
    // fused expmap0 + hyperboloid: a wave's 64 cols = one full head.
    const int head = (n0 + wn) >> 6;
    float bv[4];
#pragma unroll
    for (int j = 0; j < 4; j++) bv[j] = bias[n0 + wn + j * 16 + fr];
#pragma unroll
    for (int i = 0; i < 4; i++) {
#pragma unroll
      for (int r = 0; r < 4; r++) {
        int row = (int)m0 + wm + i * 16 + q * 4 + r;
        int b = row >> 10, s = row & 1023;
        float v0 = acc[i][0][r] + bv[0];
        float v1 = acc[i][1][r] + bv[1];
        float v2 = acc[i][2][r] + bv[2];
        float v3 = acc[i][3][r] + bv[3];
        float ss = v0 * v0 + v1 * v1 + v2 * v2 + v3 * v3;
        ss += __shfl_xor(ss, 1); ss += __shfl_xor(ss, 2);
        ss += __shfl_xor(ss, 4); ss += __shfl_xor(ss, 8);   // 64-dim row norm^2
        float n = sqrtf(fmaxf(ss, 1e-12f));
        float th = tanhf(n);
        float sq = th * th;
        float dd = fmaxf(1.f - sq, 1e-12f);
        float f = 2.f * (th / n) / dd;
        u16* base = kh + (size_t)(b * 16 + head) * 65 * 1024;
        base[(size_t)(1 + fr) * 1024 + s]  = f2bfbits(v0 * f);
        base[(size_t)(17 + fr) * 1024 + s] = f2bfbits(v1 * f);
        base[(size_t)(33 + fr) * 1024 + s] = f2bfbits(v2 * f);
        base[(size_t)(49 + fr) * 1024 + s] = f2bfbits(v3 * f);
        if (fr == 0) base[s] = f2bfbits((1.f + sq) / dd);   // kh0 (== gamma)
      }
    }
  }
}

// ---------------------------------------------------------------------------
// attention, register-resident kh. One block (256 thr) per (b,head).
// Block->XCD map matches gemm2's token->XCD map (batch-quad per XCD).
__global__ __launch_bounds__(256, 2) void attn_kernel(
    const u16* __restrict__ kh, const float* __restrict__ label,
    const int* __restrict__ y, const int* __restrict__ mask_text,
    float* __restrict__ qh_out) {
  const int g = blockIdx.x;
  const int b = (g & 7) * 4 + ((g >> 3) & 3);
  const int h = g >> 5;
  const int bh = b * 16 + h;
  const int tid = threadIdx.x, lane = tid & 63, wave = tid >> 6;
  __shared__ float qh[65], rtmp[4], redp[4][65];
  const u16* khb = kh + (size_t)bh * 65 * 1024;

  float kh0[4];
  unsigned int khp[4][32];
  int mt[4];
#pragma unroll
  for (int r = 0; r < 4; r++) {
    int s = r * 256 + tid;
    mt[r] = mask_text[b * 1024 + s];
    kh0[r] = bf2f(khb[s]);
#pragma unroll
    for (int k = 0; k < 32; k++) {
      unsigned int lo = khb[(1 + 2 * k) * 1024 + s];
      unsigned int hi = khb[(2 + 2 * k) * 1024 + s];
      khp[r][k] = lo | (hi << 16);
    }
  }

  if (wave == 0) {                         // initial lift of q = label[y[b]]
    float qv = label[(size_t)y[b] * 64 + lane];
    float sq = qv * qv;
#pragma unroll
    for (int d = 1; d < 64; d <<= 1) sq += __shfl_xor(sq, d);
    float dd = fmaxf(1.f - sq, 1e-12f);
    qh[lane + 1] = 2.f * qv / dd;
    if (lane == 0) qh[0] = (1.f + sq) / dd;
  }
  __syncthreads();

  for (int layer = 0; layer < 4; layer++) {
    float q0 = qh[0];
    float inn[4];
#pragma unroll
    for (int r = 0; r < 4; r++) inn[r] = -q0 * kh0[r];
#pragma unroll
    for (int k = 0; k < 32; k++) {
      float qa = qh[1 + 2 * k], qb = qh[2 + 2 * k];
#pragma unroll
      for (int r = 0; r < 4; r++) {
        unsigned int p = khp[r][k];
        inn[r] = fmaf(qa, __uint_as_float(p << 16),
                 fmaf(qb, __uint_as_float(p & 0xffff0000u), inn[r]));
      }
    }
    float w[4]; float lmax = -3e38f;
#pragma unroll
    for (int r = 0; r < 4; r++) {
      float x = fmaxf(-inn[r], 1.f + 1e-6f);
      float sco = -acoshf(x);
      sco = (mt[r] > 0) ? sco : -1e9f;
      w[r] = sco;
      lmax = fmaxf(lmax, sco);
    }
#pragma unroll
    for (int d = 1; d < 64; d <<= 1) lmax = fmaxf(lmax, __shfl_xor(lmax, d));
    if (lane == 0) rtmp[wave] = lmax;
    __syncthreads();
    float m = fmaxf(fmaxf(rtmp[0], rtmp[1]), fmaxf(rtmp[2], rtmp[3]));
#pragma unroll
    for (int r = 0; r < 4; r++) w[r] = __expf(w[r] - m);

    float p0 = w[0] * kh0[0] + w[1] * kh0[1] + w[2] * kh0[2] + w[3] * kh0[3];
#pragma unroll
    for (int d = 1; d < 64; d <<= 1) p0 += __shfl_xor(p0, d);
    if (lane == 0) redp[wave][0] = p0;
#pragma unroll
    for (int k = 0; k < 32; k++) {
      float pa = 0.f, pb = 0.f;
#pragma unroll
      for (int r = 0; r < 4; r++) {
        unsigned int p = khp[r][k];
        pa = fmaf(w[r], __uint_as_float(p << 16), pa);
        pb = fmaf(w[r], __uint_as_float(p & 0xffff0000u), pb);
      }
#pragma unroll
      for (int d = 1; d < 64; d <<= 1) pa += __shfl_xor(pa, d);
#pragma unroll
      for (int d = 1; d < 64; d <<= 1) pb += __shfl_xor(pb, d);
      if (lane == 0) { redp[wave][1 + 2 * k] = pa; redp[wave][2 + 2 * k] = pb; }
    }
    __syncthreads();

    if (wave == 0) {                       // Einstein midpoint + k2p + lift, fused
      float denom = redp[0][0] + redp[1][0] + redp[2][0] + redp[3][0];
      float num = redp[0][lane + 1] + redp[1][lane + 1] + redp[2][lane + 1] + redp[3][lane + 1];
      float mid = num / denom;             // Klein coords
      float kl = mid * mid;
#pragma unroll
      for (int d = 1; d < 64; d <<= 1) kl += __shfl_xor(kl, d);
      float u = sqrtf(fmaxf(1.f - kl, 1e-12f));
      float pc = mid / (1.f + u);
      float sp = kl / ((1.f + u) * (1.f + u));
      float dd = fmaxf(1.f - sp, 1e-12f);
      qh[lane + 1] = 2.f * pc / dd;
      if (lane == 0) qh[0] = (1.f + sp) / dd;
    }
    __syncthreads();
  }
  if (tid < 65) qh_out[(size_t)bh * 65 + tid] = qh[tid];
}

// ---------------------------------------------------------------------------
// label distances + aggregation MLP. Uniform operands via s_load; lh is bf16.
__global__ __launch_bounds__(256) void label_mlp(
    const float* __restrict__ qh, const u16* __restrict__ lh,
    const float* __restrict__ w1, const float* __restrict__ b1,
    const float* __restrict__ w2, const float* __restrict__ b2,
    const float* __restrict__ w3, const float* __restrict__ b3,
    const float* __restrict__ w4, const float* __restrict__ b4,
    const int* __restrict__ mask_label, float* __restrict__ out) {
  int blk = blockIdx.x;
  int b = blk >> 5, lb = blk & 31;
  int l = lb * 256 + threadIdx.x;
  const float* qb = qh + (size_t)b * 1040;

  float inner[16];
  float l0 = bf2f(lh[l]);
#pragma unroll
  for (int h = 0; h < 16; h++) inner[h] = -qb[h * 65] * l0;
  for (int c = 1; c < 65; c++) {
    float lc = bf2f(lh[(size_t)c * 8192 + l]);
#pragma unroll
    for (int h = 0; h < 16; h++) inner[h] = fmaf(qb[h * 65 + c], lc, inner[h]);
  }
  float d[16];
#pragma unroll
  for (int h = 0; h < 16; h++) d[h] = acoshf(fmaxf(-inner[h], 1.f + 1e-6f));

  float x1[32];
#pragma unroll
  for (int o = 0; o < 32; o++) {
    float a = b1[o];
#pragma unroll
    for (int h = 0; h < 16; h++) a = fmaf(d[h], w1[h * 32 + o], a);
    x1[o] = fmaxf(a, 0.f);
  }
  float x2[32];
#pragma unroll
  for (int o = 0; o < 32; o++) {
    float a = b2[o];
#pragma unroll
    for (int i = 0; i < 32; i++) a = fmaf(x1[i], w2[i * 32 + o], a);
    x2[o] = fmaxf(a, 0.f);
  }
  float x3[16];
#pragma unroll
  for (int o = 0; o < 16; o++) {
    float a = b3[o];
#pragma unroll
    for (int i = 0; i < 32; i++) a = fmaf(x2[i], w3[i * 16 + o], a);
    x3[o] = fmaxf(a, 0.f);
  }
  float acc = b4[0];
#pragma unroll
  for (int h = 0; h < 16; h++) acc = fmaf(x3[h], w4[h], acc);
  out[(size_t)b * 8192 + l] = (mask_label[(size_t)b * 8192 + l] > 0) ? acc : -500.0f;
}

// ---------------------------------------------------------------------------
extern "C" void kernel_launch(void* const* d_in, const int* in_sizes, int n_in,
                              void* d_out, int out_size, void* d_ws, size_t ws_size,
                              hipStream_t stream) {
  const float* e     = (const float*)d_in[0];
  const float* label = (const float*)d_in[1];
  const float* tc_w1 = (const float*)d_in[2];
  const float* tc_b1 = (const float*)d_in[3];
  const float* tc_w2 = (const float*)d_in[4];
  const float* tc_b2 = (const float*)d_in[5];
  const float* hyp_w = (const float*)d_in[6];
  const float* hyp_b = (const float*)d_in[7];
  const float* aw1 = (const float*)d_in[8];
  const float* ab1 = (const float*)d_in[9];
  const float* aw2 = (const float*)d_in[10];
  const float* ab2 = (const float*)d_in[11];
  const float* aw3 = (const float*)d_in[12];
  const float* ab3 = (const float*)d_in[13];
  const float* aw4 = (const float*)d_in[14];
  const float* ab4 = (const float*)d_in[15];
  const int* y          = (const int*)d_in[16];
  const int* mask_text  = (const int*)d_in[17];
  const int* mask_label = (const int*)d_in[18];
  float* out = (float*)d_out;

  char* ws = (char*)d_ws;
  // [0, 134.2MB): X (bf16 32768x2048); qh (133KB) aliases it after gemm2
  // [134.2MB, +68.2MB): ebf (64MB, dead after gemm1) overlapped by kh (68.2MB)
  u16*   X    = (u16*)(ws + 0);
  float* qh   = (float*)(ws + 0);
  u16*   ebf  = (u16*)(ws + 134217728ull);
  u16*   kh   = (u16*)(ws + 134217728ull);
  u16*   w2eT = (u16*)(ws + 202375168ull);
  u16*   w1T  = (u16*)(ws + 206569472ull);
  float* beff = (float*)(ws + 210763776ull);
  u16*   lh   = (u16*)(ws + 210767872ull);   // bf16 [65][8192] = 1.06MB

  prep_kernel<<<673 + 8192, 256, 0, stream>>>(e, tc_w1, tc_w2, tc_b2, hyp_w, hyp_b,
                                              label, ebf, w1T, w2eT, beff, lh);
  gemm_bf16<0><<<4096, 256, 0, stream>>>(ebf, w1T, tc_b1, X, nullptr, 2048, 1024);
  gemm_bf16<1><<<2048, 256, 0, stream>>>(X, w2eT, beff, nullptr, kh, 1024, 2048);
  attn_kernel<<<512, 256, 0, stream>>>(kh, label, y, mask_text, qh);
  label_mlp<<<1024, 256, 0, stream>>>(qh, lh, aw1, ab1, aw2, ab2, aw3, ab3, aw4, ab4,
                                      mask_label, out);
}

// Round 5
// 683.106 us; speedup vs baseline: 1.0863x; 1.0863x over previous
//
#include <hip/hip_runtime.h>
#include <stdint.h>

// ---------------------------------------------------------------------------
// MiniAlignDecoder on MI355X (gfx950)  — Round 5
// R5 changes vs R4 (which showed the GEMM K-loop is latency-coupled to
// concurrent HBM byte traffic: dur ≈ bytes / 1.5 TB/s in both R2 and R4):
//  * Both GEMMs switched to fp8 e4m3 MFMA (16x16x32_fp8_fp8): staging bytes
//    halve (2 global_load_lds per iter instead of 4), X 134->67 MB,
//    e 64->34 MB. Weights pre-scaled (w1 x32, w2eff x64) to sit in e4m3's
//    normal range; un-scaled in the epilogue before bias.
//  * MODE 1 kh epilogue: LDS transpose (comp-major, stride 66) ->
//    coalesced 128B wave-stores (was 320 scattered 2B stores/thread), and
//    fast tanh via __expf (was 16 libm tanhf calls/thread).
// ---------------------------------------------------------------------------

typedef unsigned short u16;
typedef unsigned char u8;
typedef long long i64;
typedef __attribute__((ext_vector_type(4))) float f32x4;

#define DEVI static __device__ __forceinline__

DEVI float bf2f(u16 u) { return __uint_as_float(((unsigned int)u) << 16); }
DEVI u16 f2bfbits(float f) {
  unsigned int x = __float_as_uint(f);
  unsigned int r = x + 0x7fffu + ((x >> 16) & 1u);   // RNE
  return (u16)(r >> 16);
}
DEVI u8 f2fp8(float f) {
  return (u8)(__builtin_amdgcn_cvt_pk_fp8_f32(f, 0.f, 0, false) & 0xff);
}
DEVI unsigned int pack4_fp8(float a, float b, float c, float d) {
  int r = __builtin_amdgcn_cvt_pk_fp8_f32(a, b, 0, false);
  r = __builtin_amdgcn_cvt_pk_fp8_f32(c, d, r, true);
  return (unsigned int)r;
}

typedef __attribute__((address_space(1))) unsigned int gu32;
typedef __attribute__((address_space(3))) unsigned int su32;
DEVI void lds_cp16(const void* g, void* l) {
  __builtin_amdgcn_global_load_lds((gu32*)g, (su32*)l, 16, 0, 0);
}

// ---------------------------------------------------------------------------
// prep: heterogeneous roles by blockIdx.x
//  [0,512)        : w1 [1024][2048] -> w1T8 fp8 [2048][1024], scaled x32
//  [512,640)      : w2eT8[n][k] = fp8(64 * sum_d w2[k][ch*64+d]*hyp_w[d][o])
//  640            : beff[n] = b2_chunk @ hyp_w + hyp_b  (fp32, unscaled)
//  [641,673)      : lh bf16 [65][8192] hyperboloid lift of labels
//  [673,673+8192) : e fp32 -> e8 fp8 (16 floats / thread)
__global__ __launch_bounds__(256) void prep_kernel(
    const float* __restrict__ e, const float* __restrict__ w1,
    const float* __restrict__ w2, const float* __restrict__ b2,
    const float* __restrict__ hw, const float* __restrict__ hb,
    const float* __restrict__ label,
    u8* __restrict__ e8, u8* __restrict__ w1T8, u8* __restrict__ w2eT8,
    float* __restrict__ beff, u16* __restrict__ lh) {
  __shared__ float t[64][65];
  const int blk = blockIdx.x;
  const int tid = threadIdx.x;

  if (blk >= 673) {                       // ---- cvt e -> fp8
    int gi = (blk - 673) * 256 + tid;     // uint4 output index
    const float4* in = (const float4*)e + (size_t)gi * 4;
    float4 f0 = in[0], f1 = in[1], f2 = in[2], f3 = in[3];
    uint4 o;
    o.x = pack4_fp8(f0.x, f0.y, f0.z, f0.w);
    o.y = pack4_fp8(f1.x, f1.y, f1.z, f1.w);
    o.z = pack4_fp8(f2.x, f2.y, f2.z, f2.w);
    o.w = pack4_fp8(f3.x, f3.y, f3.z, f3.w);
    ((uint4*)e8)[gi] = o;
  } else if (blk < 512) {                 // ---- transpose w1 -> w1T8 (x32)
    int c0 = (blk & 31) * 64, r0 = (blk >> 5) * 64;
    int tx = tid & 63, ty = tid >> 6;
#pragma unroll
    for (int i = 0; i < 16; i++) {
      int r = i * 4 + ty;
      t[r][tx] = w1[(size_t)(r0 + r) * 2048 + c0 + tx];
    }
    __syncthreads();
#pragma unroll
    for (int i = 0; i < 16; i++) {
      int c = i * 4 + ty;
      w1T8[(size_t)(c0 + c) * 1024 + r0 + tx] = f2fp8(t[tx][c] * 32.f);
    }
  } else if (blk < 640) {                 // ---- w2eff (x64)
    int bw = blk - 512;
    int ch = bw >> 3, kb = bw & 7;
    int k = kb * 256 + tid;
    float row[64];
    const float4* rp = (const float4*)(w2 + (size_t)k * 1024 + ch * 64);
#pragma unroll
    for (int i = 0; i < 16; i++) {
      float4 f = rp[i];
      row[i * 4] = f.x; row[i * 4 + 1] = f.y; row[i * 4 + 2] = f.z; row[i * 4 + 3] = f.w;
    }
    for (int o = 0; o < 64; o++) {
      float a = 0.f;
#pragma unroll
      for (int d = 0; d < 64; d++) a = fmaf(row[d], hw[d * 64 + o], a);
      w2eT8[(size_t)(ch * 64 + o) * 2048 + k] = f2fp8(a * 64.f);
    }
  } else if (blk == 640) {                // ---- beff
    for (int n = tid; n < 1024; n += 256) {
      int ch = n >> 6, o = n & 63;
      float a = hb[o];
#pragma unroll
      for (int d = 0; d < 64; d++) a += b2[ch * 64 + d] * hw[d * 64 + o];
      beff[n] = a;
    }
  } else {                                // ---- lh (bf16)
    int l = (blk - 641) * 256 + tid;
    const float4* lp = (const float4*)(label + (size_t)l * 64);
    float v[64]; float sq = 0.f;
#pragma unroll
    for (int i = 0; i < 16; i++) {
      float4 f = lp[i];
      v[i * 4] = f.x; v[i * 4 + 1] = f.y; v[i * 4 + 2] = f.z; v[i * 4 + 3] = f.w;
      sq += f.x * f.x + f.y * f.y + f.z * f.z + f.w * f.w;
    }
    float dd = fmaxf(1.f - sq, 1e-12f);
    lh[l] = f2bfbits((1.f + sq) / dd);
#pragma unroll
    for (int c = 0; c < 64; c++) lh[(size_t)(c + 1) * 8192 + l] = f2bfbits(2.f * v[c] / dd);
  }
}

// ---------------------------------------------------------------------------
// MFMA fp8 GEMM: BK=32, 128x128 tile, 4 waves (2x2), 4x4 MFMA 16x16x32_fp8.
// Staging: ONE global_load_lds(16B) per matrix per iter (128 rows x 32B).
// XCD swizzle as before. acc is un-scaled by inv_scale in the epilogue.
// MODE 0: relu(acc*inv_scale + bias) -> C fp8.
// MODE 1: expmap0 + hyperboloid lift; LDS-transposed coalesced kh writes.
template <int MODE>
__global__ __launch_bounds__(256, 2) void gemm_fp8(
    const u8* __restrict__ A, const u8* __restrict__ Bt,
    const float* __restrict__ bias, u8* __restrict__ C,
    u16* __restrict__ kh, int N, int K, float inv_scale) {
  __shared__ u8 As[128 * 32];
  __shared__ u8 Bs[128 * 32];
  const int tid = threadIdx.x;
  const int wave = tid >> 6, lane = tid & 63;
  const int fr = lane & 15, q = lane >> 4;
  const int nblk = N >> 7;
  const int g = blockIdx.x;
  const int xcd = g & 7;
  const int t = g >> 3;
  const int per = (gridDim.x >> 3) / nblk;     // bm rows per XCD
  const int bm = xcd * per + t / nblk;
  const int bn = t % nblk;
  const size_t m0 = (size_t)bm * 128;
  const int n0 = bn * 128;
  const int wm = (wave >> 1) << 6, wn = (wave & 1) << 6;
  f32x4 acc[4][4] = {};

  // staging: lane -> row = tid>>1, 16B chunk = (tid&1)*16; LDS row-major [128][32]B
  const int r0 = tid >> 1, o0 = (tid & 1) << 4;
  const u8* Ap = A + (m0 + r0) * (size_t)K + o0;
  const u8* Bp = Bt + ((size_t)n0 + r0) * K + o0;
  u8* as = As + wave * 1024;                   // wave-uniform base (+lane*16 in HW)
  u8* bs = Bs + wave * 1024;

  for (int kk = 0; kk < K; kk += 32) {
    lds_cp16(Ap, as); lds_cp16(Bp, bs);
    Ap += 32; Bp += 32;
    __syncthreads();   // drains vmcnt(0): staged data visible
    i64 af[4], bf[4];
#pragma unroll
    for (int t2 = 0; t2 < 4; t2++) af[t2] = *(const i64*)(As + (wm + t2 * 16 + fr) * 32 + q * 8);
#pragma unroll
    for (int t2 = 0; t2 < 4; t2++) bf[t2] = *(const i64*)(Bs + (wn + t2 * 16 + fr) * 32 + q * 8);
#pragma unroll
    for (int i = 0; i < 4; i++)
#pragma unroll
      for (int j = 0; j < 4; j++)
        acc[i][j] = __builtin_amdgcn_mfma_f32_16x16x32_fp8_fp8(af[i], bf[j], acc[i][j], 0, 0, 0);
    __syncthreads();   // all waves done reading before next stage overwrites
  }

  // C/D layout: col = n0+wn+j*16+fr, row = m0+wm+i*16+q*4+r  [m89-verified]
  if (MODE == 0) {
#pragma unroll
    for (int j = 0; j < 4; j++) {
      int col = n0 + wn + j * 16 + fr;
      float bv = bias[col];
#pragma unroll
      for (int i = 0; i < 4; i++) {
#pragma unroll
        for (int r = 0; r < 4; r++) {
          size_t row = m0 + wm + i * 16 + q * 4 + r;
          float v = fmaxf(acc[i][j][r] * inv_scale + bv, 0.f);
          C[row * N + col] = f2fp8(v);
        }
      }
    }
  } else {
    // fused expmap0 + hyperboloid; wave's 64 cols = one full head.
    __shared__ __attribute__((aligned(16))) u16 eps[4][64 * 66]; // [wave][comp*66+token]
    __shared__ __attribute__((aligned(16))) unsigned int k0u[4][32];
    const int head = (n0 + wn) >> 6;
    float bv[4];
#pragma unroll
    for (int j = 0; j < 4; j++) bv[j] = bias[n0 + wn + j * 16 + fr];
    u16* ew = eps[wave];
    u16* k0w = (u16*)&k0u[wave][0];
#pragma unroll
    for (int i = 0; i < 4; i++) {
#pragma unroll
      for (int r = 0; r < 4; r++) {
        int trow = i * 16 + q * 4 + r;           // wave-local token 0..63
        float v0 = acc[i][0][r] * inv_scale + bv[0];
        float v1 = acc[i][1][r] * inv_scale + bv[1];
        float v2 = acc[i][2][r] * inv_scale + bv[2];
        float v3 = acc[i][3][r] * inv_scale + bv[3];
        float ss = v0 * v0 + v1 * v1 + v2 * v2 + v3 * v3;
        ss += __shfl_xor(ss, 1); ss += __shfl_xor(ss, 2);
        ss += __shfl_xor(ss, 4); ss += __shfl_xor(ss, 8);   // 64-dim row norm^2
        float n = sqrtf(fmaxf(ss, 1e-12f));
        float ex = __expf(-2.f * n);
        float th = (1.f - ex) / (1.f + ex);                 // tanh(n)
        float sq = th * th;
        float dd = fmaxf(1.f - sq, 1e-12f);
        float f = 2.f * (th / n) / dd;
        ew[(0 * 16 + fr) * 66 + trow] = f2bfbits(v0 * f);
        ew[(1 * 16 + fr) * 66 + trow] = f2bfbits(v1 * f);
        ew[(2 * 16 + fr) * 66 + trow] = f2bfbits(v2 * f);
        ew[(3 * 16 + fr) * 66 + trow] = f2bfbits(v3 * f);
        if (fr == 0) k0w[trow] = f2bfbits((1.f + sq) / dd); // kh0 (== gamma)
      }
    }
    __syncthreads();
    // coalesced store: 2 comps x 64 tokens per instruction (u32 = 2 bf16)
    const int rb = (int)m0 + wm;
    const int b = rb >> 10, s0 = rb & 1023;
    u16* base = kh + (size_t)(b * 16 + head) * 65 * 1024;
    const int cofs = lane >> 5;            // half-wave -> comp parity
    const int tofs = (lane & 31) * 2;      // token pair
#pragma unroll
    for (int it = 0; it < 32; it++) {
      int c = it * 2 + cofs;
      unsigned int dat = *(const unsigned int*)(ew + c * 66 + tofs);
      *(unsigned int*)(base + (size_t)(1 + c) * 1024 + s0 + tofs) = dat;
    }
    if (lane < 32) {
      unsigned int dat = k0u[wave][lane];
      *(unsigned int*)(base + s0 + lane * 2) = dat;
    }
  }
}

// ---------------------------------------------------------------------------
// attention, register-resident kh. One block (256 thr) per (b,head).
// Block->XCD map matches gemm2's token->XCD map (batch-quad per XCD).
__global__ __launch_bounds__(256, 2) void attn_kernel(
    const u16* __restrict__ kh, const float* __restrict__ label,
    const int* __restrict__ y, const int* __restrict__ mask_text,
    float* __restrict__ qh_out) {
  const int g = blockIdx.x;
  const int b = (g & 7) * 4 + ((g >> 3) & 3);
  const int h = g >> 5;
  const int bh = b * 16 + h;
  const int tid = threadIdx.x, lane = tid & 63, wave = tid >> 6;
  __shared__ float qh[65], rtmp[4], redp[4][65];
  const u16* khb = kh + (size_t)bh * 65 * 1024;

  float kh0[4];
  unsigned int khp[4][32];
  int mt[4];
#pragma unroll
  for (int r = 0; r < 4; r++) {
    int s = r * 256 + tid;
    mt[r] = mask_text[b * 1024 + s];
    kh0[r] = bf2f(khb[s]);
#pragma unroll
    for (int k = 0; k < 32; k++) {
      unsigned int lo = khb[(1 + 2 * k) * 1024 + s];
      unsigned int hi = khb[(2 + 2 * k) * 1024 + s];
      khp[r][k] = lo | (hi << 16);
    }
  }

  if (wave == 0) {                         // initial lift of q = label[y[b]]
    float qv = label[(size_t)y[b] * 64 + lane];
    float sq = qv * qv;
#pragma unroll
    for (int d = 1; d < 64; d <<= 1) sq += __shfl_xor(sq, d);
    float dd = fmaxf(1.f - sq, 1e-12f);
    qh[lane + 1] = 2.f * qv / dd;
    if (lane == 0) qh[0] = (1.f + sq) / dd;
  }
  __syncthreads();

  for (int layer = 0; layer < 4; layer++) {
    float q0 = qh[0];
    float inn[4];
#pragma unroll
    for (int r = 0; r < 4; r++) inn[r] = -q0 * kh0[r];
#pragma unroll
    for (int k = 0; k < 32; k++) {
      float qa = qh[1 + 2 * k], qb = qh[2 + 2 * k];
#pragma unroll
      for (int r = 0; r < 4; r++) {
        unsigned int p = khp[r][k];
        inn[r] = fmaf(qa, __uint_as_float(p << 16),
                 fmaf(qb, __uint_as_float(p & 0xffff0000u), inn[r]));
      }
    }
    float w[4]; float lmax = -3e38f;
#pragma unroll
    for (int r = 0; r < 4; r++) {
      float x = fmaxf(-inn[r], 1.f + 1e-6f);
      float sco = -acoshf(x);
      sco = (mt[r] > 0) ? sco : -1e9f;
      w[r] = sco;
      lmax = fmaxf(lmax, sco);
    }
#pragma unroll
    for (int d = 1; d < 64; d <<= 1) lmax = fmaxf(lmax, __shfl_xor(lmax, d));
    if (lane == 0) rtmp[wave] = lmax;
    __syncthreads();
    float m = fmaxf(fmaxf(rtmp[0], rtmp[1]), fmaxf(rtmp[2], rtmp[3]));
#pragma unroll
    for (int r = 0; r < 4; r++) w[r] = __expf(w[r] - m);

    float p0 = w[0] * kh0[0] + w[1] * kh0[1] + w[2] * kh0[2] + w[3] * kh0[3];
#pragma unroll
    for (int d = 1; d < 64; d <<= 1) p0 += __shfl_xor(p0, d);
    if (lane == 0) redp[wave][0] = p0;
#pragma unroll
    for (int k = 0; k < 32; k++) {
      float pa = 0.f, pb = 0.f;
#pragma unroll
      for (int r = 0; r < 4; r++) {
        unsigned int p = khp[r][k];
        pa = fmaf(w[r], __uint_as_float(p << 16), pa);
        pb = fmaf(w[r], __uint_as_float(p & 0xffff0000u), pb);
      }
#pragma unroll
      for (int d = 1; d < 64; d <<= 1) pa += __shfl_xor(pa, d);
#pragma unroll
      for (int d = 1; d < 64; d <<= 1) pb += __shfl_xor(pb, d);
      if (lane == 0) { redp[wave][1 + 2 * k] = pa; redp[wave][2 + 2 * k] = pb; }
    }
    __syncthreads();

    if (wave == 0) {                       // Einstein midpoint + k2p + lift, fused
      float denom = redp[0][0] + redp[1][0] + redp[2][0] + redp[3][0];
      float num = redp[0][lane + 1] + redp[1][lane + 1] + redp[2][lane + 1] + redp[3][lane + 1];
      float mid = num / denom;             // Klein coords
      float kl = mid * mid;
#pragma unroll
      for (int d = 1; d < 64; d <<= 1) kl += __shfl_xor(kl, d);
      float u = sqrtf(fmaxf(1.f - kl, 1e-12f));
      float pc = mid / (1.f + u);
      float sp = kl / ((1.f + u) * (1.f + u));
      float dd = fmaxf(1.f - sp, 1e-12f);
      qh[lane + 1] = 2.f * pc / dd;
      if (lane == 0) qh[0] = (1.f + sp) / dd;
    }
    __syncthreads();
  }
  if (tid < 65) qh_out[(size_t)bh * 65 + tid] = qh[tid];
}

// ---------------------------------------------------------------------------
// label distances + aggregation MLP. Uniform operands via s_load; lh is bf16.
__global__ __launch_bounds__(256) void label_mlp(
    const float* __restrict__ qh, const u16* __restrict__ lh,
    const float* __restrict__ w1, const float* __restrict__ b1,
    const float* __restrict__ w2, const float* __restrict__ b2,
    const float* __restrict__ w3, const float* __restrict__ b3,
    const float* __restrict__ w4, const float* __restrict__ b4,
    const int* __restrict__ mask_label, float* __restrict__ out) {
  int blk = blockIdx.x;
  int b = blk >> 5, lb = blk & 31;
  int l = lb * 256 + threadIdx.x;
  const float* qb = qh + (size_t)b * 1040;

  float inner[16];
  float l0 = bf2f(lh[l]);
#pragma unroll
  for (int h = 0; h < 16; h++) inner[h] = -qb[h * 65] * l0;
  for (int c = 1; c < 65; c++) {
    float lc = bf2f(lh[(size_t)c * 8192 + l]);
#pragma unroll
    for (int h = 0; h < 16; h++) inner[h] = fmaf(qb[h * 65 + c], lc, inner[h]);
  }
  float d[16];
#pragma unroll
  for (int h = 0; h < 16; h++) d[h] = acoshf(fmaxf(-inner[h], 1.f + 1e-6f));

  float x1[32];
#pragma unroll
  for (int o = 0; o < 32; o++) {
    float a = b1[o];
#pragma unroll
    for (int h = 0; h < 16; h++) a = fmaf(d[h], w1[h * 32 + o], a);
    x1[o] = fmaxf(a, 0.f);
  }
  float x2[32];
#pragma unroll
  for (int o = 0; o < 32; o++) {
    float a = b2[o];
#pragma unroll
    for (int i = 0; i < 32; i++) a = fmaf(x1[i], w2[i * 32 + o], a);
    x2[o] = fmaxf(a, 0.f);
  }
  float x3[16];
#pragma unroll
  for (int o = 0; o < 16; o++) {
    float a = b3[o];
#pragma unroll
    for (int i = 0; i < 32; i++) a = fmaf(x2[i], w3[i * 16 + o], a);
    x3[o] = fmaxf(a, 0.f);
  }
  float acc = b4[0];
#pragma unroll
  for (int h = 0; h < 16; h++) acc = fmaf(x3[h], w4[h], acc);
  out[(size_t)b * 8192 + l] = (mask_label[(size_t)b * 8192 + l] > 0) ? acc : -500.0f;
}

// ---------------------------------------------------------------------------
extern "C" void kernel_launch(void* const* d_in, const int* in_sizes, int n_in,
                              void* d_out, int out_size, void* d_ws, size_t ws_size,
                              hipStream_t stream) {
  const float* e     = (const float*)d_in[0];
  const float* label = (const float*)d_in[1];
  const float* tc_w1 = (const float*)d_in[2];
  const float* tc_b1 = (const float*)d_in[3];
  const float* tc_w2 = (const float*)d_in[4];
  const float* tc_b2 = (const float*)d_in[5];
  const float* hyp_w = (const float*)d_in[6];
  const float* hyp_b = (const float*)d_in[7];
  const float* aw1 = (const float*)d_in[8];
  const float* ab1 = (const float*)d_in[9];
  const float* aw2 = (const float*)d_in[10];
  const float* ab2 = (const float*)d_in[11];
  const float* aw3 = (const float*)d_in[12];
  const float* ab3 = (const float*)d_in[13];
  const float* aw4 = (const float*)d_in[14];
  const float* ab4 = (const float*)d_in[15];
  const int* y          = (const int*)d_in[16];
  const int* mask_text  = (const int*)d_in[17];
  const int* mask_label = (const int*)d_in[18];
  float* out = (float*)d_out;

  char* ws = (char*)d_ws;
  // [0, 67.1MB): X8 (fp8 32768x2048); qh (133KB) aliases it after gemm2
  // [67.1MB, 135.3MB): kh bf16 [512][65][1024]
  // [135.3MB, 168.8MB): e8 fp8 [32768][1024]
  u8*    X8    = (u8*)(ws + 0);
  float* qh    = (float*)(ws + 0);
  u16*   kh    = (u16*)(ws + 67108864ull);
  u8*    e8    = (u8*)(ws + 135266304ull);
  u8*    w1T8  = (u8*)(ws + 168820736ull);
  u8*    w2eT8 = (u8*)(ws + 170917888ull);
  float* beff  = (float*)(ws + 173015040ull);
  u16*   lh    = (u16*)(ws + 173019136ull);   // bf16 [65][8192] = 1.06MB

  prep_kernel<<<673 + 8192, 256, 0, stream>>>(e, tc_w1, tc_w2, tc_b2, hyp_w, hyp_b,
                                              label, e8, w1T8, w2eT8, beff, lh);
  gemm_fp8<0><<<4096, 256, 0, stream>>>(e8, w1T8, tc_b1, X8, nullptr, 2048, 1024,
                                        1.f / 32.f);
  gemm_fp8<1><<<2048, 256, 0, stream>>>(X8, w2eT8, beff, nullptr, kh, 1024, 2048,
                                        1.f / 64.f);
  attn_kernel<<<512, 256, 0, stream>>>(kh, label, y, mask_text, qh);
  label_mlp<<<1024, 256, 0, stream>>>(qh, lh, aw1, ab1, aw2, ab2, aw3, ab3, aw4, ab4,
                                      mask_label, out);
}

// Round 6
// 545.665 us; speedup vs baseline: 1.3599x; 1.2519x over previous
//
#include <hip/hip_runtime.h>
#include <stdint.h>

// ---------------------------------------------------------------------------
// MiniAlignDecoder on MI355X (gfx950)  — Round 6
// R6 changes vs R5 (gemm pinned at 188 µs regardless of dtype/bytes ->
// barrier-drain latency x iteration count is the binding constraint):
//  * GEMMs -> MX-scaled fp8 K=128 (mfma_scale_f32_16x16x128_f8f6f4, fmt fp8):
//    4x fewer K-iterations/barriers, 2x MFMA rate class (m148: 1628 TF).
//    Uniform E8M0 scale bytes (replicated -> opsel-immune); B-side scale
//    2^-5 / 2^-6 cancels the w1 x32 / w2eff x64 fp8-range pre-scaling.
//  * One 32 KB SMEM block, epilogue reuses it (R5 bug: MODE 0 carried the
//    epilogue's 34 KB LDS -> occupancy 40->30%). if constexpr everywhere.
//  * XOR 16B-chunk swizzle on 128 B LDS rows: fragment ds_read_b128 goes
//    16-way -> 2-way (free). Staging stays 128 B-coalesced per row.
//  * MODE 1 kh epilogue: staged 16-comps-per-pass LDS transpose, coalesced
//    u32 wave-stores.
// ---------------------------------------------------------------------------

typedef unsigned short u16;
typedef unsigned char u8;
typedef __attribute__((ext_vector_type(4))) float f32x4;
typedef __attribute__((ext_vector_type(4))) int i32x4;
typedef __attribute__((ext_vector_type(8))) int i32x8;

#define DEVI static __device__ __forceinline__

DEVI float bf2f(u16 u) { return __uint_as_float(((unsigned int)u) << 16); }
DEVI u16 f2bfbits(float f) {
  unsigned int x = __float_as_uint(f);
  unsigned int r = x + 0x7fffu + ((x >> 16) & 1u);   // RNE
  return (u16)(r >> 16);
}
DEVI u8 f2fp8(float f) {
  return (u8)(__builtin_amdgcn_cvt_pk_fp8_f32(f, 0.f, 0, false) & 0xff);
}
DEVI unsigned int pack4_fp8(float a, float b, float c, float d) {
  int r = __builtin_amdgcn_cvt_pk_fp8_f32(a, b, 0, false);
  r = __builtin_amdgcn_cvt_pk_fp8_f32(c, d, r, true);
  return (unsigned int)r;
}

typedef __attribute__((address_space(1))) unsigned int gu32;
typedef __attribute__((address_space(3))) unsigned int su32;
DEVI void lds_cp16(const void* g, void* l) {
  __builtin_amdgcn_global_load_lds((gu32*)g, (su32*)l, 16, 0, 0);
}

// ---------------------------------------------------------------------------
// prep: heterogeneous roles by blockIdx.x (unchanged from R5)
__global__ __launch_bounds__(256) void prep_kernel(
    const float* __restrict__ e, const float* __restrict__ w1,
    const float* __restrict__ w2, const float* __restrict__ b2,
    const float* __restrict__ hw, const float* __restrict__ hb,
    const float* __restrict__ label,
    u8* __restrict__ e8, u8* __restrict__ w1T8, u8* __restrict__ w2eT8,
    float* __restrict__ beff, u16* __restrict__ lh) {
  __shared__ float t[64][65];
  const int blk = blockIdx.x;
  const int tid = threadIdx.x;

  if (blk >= 673) {                       // ---- cvt e -> fp8
    int gi = (blk - 673) * 256 + tid;     // uint4 output index
    const float4* in = (const float4*)e + (size_t)gi * 4;
    float4 f0 = in[0], f1 = in[1], f2 = in[2], f3 = in[3];
    uint4 o;
    o.x = pack4_fp8(f0.x, f0.y, f0.z, f0.w);
    o.y = pack4_fp8(f1.x, f1.y, f1.z, f1.w);
    o.z = pack4_fp8(f2.x, f2.y, f2.z, f2.w);
    o.w = pack4_fp8(f3.x, f3.y, f3.z, f3.w);
    ((uint4*)e8)[gi] = o;
  } else if (blk < 512) {                 // ---- transpose w1 -> w1T8 (x32)
    int c0 = (blk & 31) * 64, r0 = (blk >> 5) * 64;
    int tx = tid & 63, ty = tid >> 6;
#pragma unroll
    for (int i = 0; i < 16; i++) {
      int r = i * 4 + ty;
      t[r][tx] = w1[(size_t)(r0 + r) * 2048 + c0 + tx];
    }
    __syncthreads();
#pragma unroll
    for (int i = 0; i < 16; i++) {
      int c = i * 4 + ty;
      w1T8[(size_t)(c0 + c) * 1024 + r0 + tx] = f2fp8(t[tx][c] * 32.f);
    }
  } else if (blk < 640) {                 // ---- w2eff (x64)
    int bw = blk - 512;
    int ch = bw >> 3, kb = bw & 7;
    int k = kb * 256 + tid;
    float row[64];
    const float4* rp = (const float4*)(w2 + (size_t)k * 1024 + ch * 64);
#pragma unroll
    for (int i = 0; i < 16; i++) {
      float4 f = rp[i];
      row[i * 4] = f.x; row[i * 4 + 1] = f.y; row[i * 4 + 2] = f.z; row[i * 4 + 3] = f.w;
    }
    for (int o = 0; o < 64; o++) {
      float a = 0.f;
#pragma unroll
      for (int d = 0; d < 64; d++) a = fmaf(row[d], hw[d * 64 + o], a);
      w2eT8[(size_t)(ch * 64 + o) * 2048 + k] = f2fp8(a * 64.f);
    }
  } else if (blk == 640) {                // ---- beff
    for (int n = tid; n < 1024; n += 256) {
      int ch = n >> 6, o = n & 63;
      float a = hb[o];
#pragma unroll
      for (int d = 0; d < 64; d++) a += b2[ch * 64 + d] * hw[d * 64 + o];
      beff[n] = a;
    }
  } else {                                // ---- lh (bf16)
    int l = (blk - 641) * 256 + tid;
    const float4* lp = (const float4*)(label + (size_t)l * 64);
    float v[64]; float sq = 0.f;
#pragma unroll
    for (int i = 0; i < 16; i++) {
      float4 f = lp[i];
      v[i * 4] = f.x; v[i * 4 + 1] = f.y; v[i * 4 + 2] = f.z; v[i * 4 + 3] = f.w;
      sq += f.x * f.x + f.y * f.y + f.z * f.z + f.w * f.w;
    }
    float dd = fmaxf(1.f - sq, 1e-12f);
    lh[l] = f2bfbits((1.f + sq) / dd);
#pragma unroll
    for (int c = 0; c < 64; c++) lh[(size_t)(c + 1) * 8192 + l] = f2bfbits(2.f * v[c] / dd);
  }
}

// ---------------------------------------------------------------------------
// MX-scaled fp8 GEMM: K=128/iter, 128x128 tile, 4 waves (2x2), 4x4 MFMA
// 16x16x128 per wave. LDS rows 128 B with XOR 16B-chunk swizzle
// (pos = chunk ^ (row&7)): staging keeps per-row 128 B coalescing, fragment
// b128 reads spread 16-way -> 2-way (free). Scales: sa = 1.0 (0x7F bytes),
// sb passed in (cancels weight pre-scale). XCD swizzle as R2-R5.
// MODE 0: relu(acc+bias) -> C fp8.  MODE 1: expmap0+hyperboloid -> kh bf16.
template <int MODE>
__global__ __launch_bounds__(256, 4) void gemm_mx(
    const u8* __restrict__ A, const u8* __restrict__ Bt,
    const float* __restrict__ bias, u8* __restrict__ C,
    u16* __restrict__ kh, int N, int K, unsigned int sb_scale) {
  __shared__ __attribute__((aligned(16))) u8 SM[32768];
  u8* As = SM;                 // [128][128] fp8, chunk-swizzled
  u8* Bs = SM + 16384;
  const int tid = threadIdx.x;
  const int wave = tid >> 6, lane = tid & 63;
  const int fr = lane & 15, q = lane >> 4;
  const int nblk = N >> 7;
  const int g = blockIdx.x;
  const int xcd = g & 7;
  const int t = g >> 3;
  const int per = (gridDim.x >> 3) / nblk;     // bm rows per XCD
  const int bm = xcd * per + t / nblk;
  const int bn = t % nblk;
  const size_t m0 = (size_t)bm * 128;
  const int n0 = bn * 128;
  const int wm = (wave >> 1) << 6, wn = (wave & 1) << 6;
  f32x4 acc[4][4] = {};

  // staging: call c covers rows [c*32, c*32+32); lane: row = c*32 + (tid>>3),
  // LDS pos = tid&7, source chunk = pos ^ (row&7)  (c*32 = 0 mod 8)
  const int srow = tid >> 3;
  const int schunk = (tid & 7) ^ (srow & 7);
  const u8* Ap = A + (m0 + srow) * (size_t)K + schunk * 16;
  const u8* Bp = Bt + ((size_t)n0 + srow) * K + schunk * 16;

  // fragment read base: row = wm|wn + t2*16 + fr (row&7 == fr&7), lane's
  // 32 K-bytes = chunks {2q, 2q+1} -> swizzled positions, hi = lo ^ 16
  const int aL = (wm + fr) * 128 + ((((q << 1)) ^ (fr & 7)) << 4);
  const int bL = (wn + fr) * 128 + ((((q << 1)) ^ (fr & 7)) << 4);

  for (int kk = 0; kk < K; kk += 128) {
#pragma unroll
    for (int c = 0; c < 4; c++) {
      lds_cp16(Ap + (size_t)c * 32 * K, As + c * 4096 + wave * 1024);
      lds_cp16(Bp + (size_t)c * 32 * K, Bs + c * 4096 + wave * 1024);
    }
    Ap += 128; Bp += 128;
    __syncthreads();   // staged data visible
    i32x8 af[4], bf[4];
#pragma unroll
    for (int t2 = 0; t2 < 4; t2++) {
      i32x4 lo = *(const i32x4*)(As + aL + t2 * 2048);
      i32x4 hi = *(const i32x4*)(As + (aL ^ 16) + t2 * 2048);
      af[t2] = __builtin_shufflevector(lo, hi, 0, 1, 2, 3, 4, 5, 6, 7);
      i32x4 lo2 = *(const i32x4*)(Bs + bL + t2 * 2048);
      i32x4 hi2 = *(const i32x4*)(Bs + (bL ^ 16) + t2 * 2048);
      bf[t2] = __builtin_shufflevector(lo2, hi2, 0, 1, 2, 3, 4, 5, 6, 7);
    }
#pragma unroll
    for (int i = 0; i < 4; i++)
#pragma unroll
      for (int j = 0; j < 4; j++)
        acc[i][j] = __builtin_amdgcn_mfma_scale_f32_16x16x128_f8f6f4(
            af[i], bf[j], acc[i][j], 0, 0,            // fmt A=fp8, fmt B=fp8
            0, 0x7F7F7F7F,                            // scale A = 2^0
            0, (int)sb_scale);                        // scale B (replicated)
    __syncthreads();   // all reads done before next stage overwrites
  }

  // C/D layout: col = n0+wn+j*16+fr, row = m0+wm+i*16+q*4+r  [m89-verified]
  if constexpr (MODE == 0) {
#pragma unroll
    for (int j = 0; j < 4; j++) {
      int col = n0 + wn + j * 16 + fr;
      float bv = bias[col];
#pragma unroll
      for (int i = 0; i < 4; i++) {
#pragma unroll
        for (int r = 0; r < 4; r++) {
          size_t row = m0 + wm + i * 16 + q * 4 + r;
          C[row * N + col] = f2fp8(fmaxf(acc[i][j][r] + bv, 0.f));
        }
      }
    }
  } else {
    // fused expmap0 + hyperboloid; wave's 64 cols = one full head.
    // Reuse SM (dead after K-loop's final barrier): ew = [4][16][66] u16
    // (one 16-comp j-pass per wave), k0w = [4][64] u16 at +9216.
    u16* ew = (u16*)SM;
    u16* k0w = (u16*)(SM + 9216);
    const int head = (n0 + wn) >> 6;
    const int rb = (int)m0 + wm;
    const int b = rb >> 10, s0 = rb & 1023;
    u16* base = kh + (size_t)(b * 16 + head) * 65 * 1024;
    float bv[4];
#pragma unroll
    for (int j = 0; j < 4; j++) bv[j] = bias[n0 + wn + j * 16 + fr];

    float ff[4][4];
#pragma unroll
    for (int i = 0; i < 4; i++) {
#pragma unroll
      for (int r = 0; r < 4; r++) {
        float v0 = acc[i][0][r] + bv[0];
        float v1 = acc[i][1][r] + bv[1];
        float v2 = acc[i][2][r] + bv[2];
        float v3 = acc[i][3][r] + bv[3];
        float ss = v0 * v0 + v1 * v1 + v2 * v2 + v3 * v3;
        ss += __shfl_xor(ss, 1); ss += __shfl_xor(ss, 2);
        ss += __shfl_xor(ss, 4); ss += __shfl_xor(ss, 8);  // 64-dim norm^2
        float n = sqrtf(fmaxf(ss, 1e-12f));
        float ex = __expf(-2.f * n);
        float th = (1.f - ex) / (1.f + ex);                // tanh(n)
        float sq = th * th;
        float dd = fmaxf(1.f - sq, 1e-12f);
        ff[i][r] = 2.f * (th / n) / dd;
        if (fr == 0) k0w[wave * 64 + i * 16 + q * 4 + r] = f2bfbits((1.f + sq) / dd);
      }
    }
#pragma unroll
    for (int j = 0; j < 4; j++) {
#pragma unroll
      for (int i = 0; i < 4; i++)
#pragma unroll
        for (int r = 0; r < 4; r++) {
          int trow = i * 16 + q * 4 + r;
          ew[wave * 1056 + fr * 66 + trow] =
              f2bfbits((acc[i][j][r] + bv[j]) * ff[i][r]);
        }
      __syncthreads();
#pragma unroll
      for (int it = 0; it < 8; it++) {
        int c2 = it * 2 + (lane >> 5);
        int tok = (lane & 31) * 2;
        unsigned int dat = *(const unsigned int*)(ew + wave * 1056 + c2 * 66 + tok);
        *(unsigned int*)(base + (size_t)(1 + j * 16 + c2) * 1024 + s0 + tok) = dat;
      }
      __syncthreads();
    }
    if (lane < 32) {
      unsigned int dat = *(const unsigned int*)(k0w + wave * 64 + lane * 2);
      *(unsigned int*)(base + s0 + lane * 2) = dat;     // kh0 (== gamma)
    }
  }
}

// ---------------------------------------------------------------------------
// attention, register-resident kh (unchanged from R5)
__global__ __launch_bounds__(256, 2) void attn_kernel(
    const u16* __restrict__ kh, const float* __restrict__ label,
    const int* __restrict__ y, const int* __restrict__ mask_text,
    float* __restrict__ qh_out) {
  const int g = blockIdx.x;
  const int b = (g & 7) * 4 + ((g >> 3) & 3);
  const int h = g >> 5;
  const int bh = b * 16 + h;
  const int tid = threadIdx.x, lane = tid & 63, wave = tid >> 6;
  __shared__ float qh[65], rtmp[4], redp[4][65];
  const u16* khb = kh + (size_t)bh * 65 * 1024;

  float kh0[4];
  unsigned int khp[4][32];
  int mt[4];
#pragma unroll
  for (int r = 0; r < 4; r++) {
    int s = r * 256 + tid;
    mt[r] = mask_text[b * 1024 + s];
    kh0[r] = bf2f(khb[s]);
#pragma unroll
    for (int k = 0; k < 32; k++) {
      unsigned int lo = khb[(1 + 2 * k) * 1024 + s];
      unsigned int hi = khb[(2 + 2 * k) * 1024 + s];
      khp[r][k] = lo | (hi << 16);
    }
  }

  if (wave == 0) {                         // initial lift of q = label[y[b]]
    float qv = label[(size_t)y[b] * 64 + lane];
    float sq = qv * qv;
#pragma unroll
    for (int d = 1; d < 64; d <<= 1) sq += __shfl_xor(sq, d);
    float dd = fmaxf(1.f - sq, 1e-12f);
    qh[lane + 1] = 2.f * qv / dd;
    if (lane == 0) qh[0] = (1.f + sq) / dd;
  }
  __syncthreads();

  for (int layer = 0; layer < 4; layer++) {
    float q0 = qh[0];
    float inn[4];
#pragma unroll
    for (int r = 0; r < 4; r++) inn[r] = -q0 * kh0[r];
#pragma unroll
    for (int k = 0; k < 32; k++) {
      float qa = qh[1 + 2 * k], qb = qh[2 + 2 * k];
#pragma unroll
      for (int r = 0; r < 4; r++) {
        unsigned int p = khp[r][k];
        inn[r] = fmaf(qa, __uint_as_float(p << 16),
                 fmaf(qb, __uint_as_float(p & 0xffff0000u), inn[r]));
      }
    }
    float w[4]; float lmax = -3e38f;
#pragma unroll
    for (int r = 0; r < 4; r++) {
      float x = fmaxf(-inn[r], 1.f + 1e-6f);
      float sco = -acoshf(x);
      sco = (mt[r] > 0) ? sco : -1e9f;
      w[r] = sco;
      lmax = fmaxf(lmax, sco);
    }
#pragma unroll
    for (int d = 1; d < 64; d <<= 1) lmax = fmaxf(lmax, __shfl_xor(lmax, d));
    if (lane == 0) rtmp[wave] = lmax;
    __syncthreads();
    float m = fmaxf(fmaxf(rtmp[0], rtmp[1]), fmaxf(rtmp[2], rtmp[3]));
#pragma unroll
    for (int r = 0; r < 4; r++) w[r] = __expf(w[r] - m);

    float p0 = w[0] * kh0[0] + w[1] * kh0[1] + w[2] * kh0[2] + w[3] * kh0[3];
#pragma unroll
    for (int d = 1; d < 64; d <<= 1) p0 += __shfl_xor(p0, d);
    if (lane == 0) redp[wave][0] = p0;
#pragma unroll
    for (int k = 0; k < 32; k++) {
      float pa = 0.f, pb = 0.f;
#pragma unroll
      for (int r = 0; r < 4; r++) {
        unsigned int p = khp[r][k];
        pa = fmaf(w[r], __uint_as_float(p << 16), pa);
        pb = fmaf(w[r], __uint_as_float(p & 0xffff0000u), pb);
      }
#pragma unroll
      for (int d = 1; d < 64; d <<= 1) pa += __shfl_xor(pa, d);
#pragma unroll
      for (int d = 1; d < 64; d <<= 1) pb += __shfl_xor(pb, d);
      if (lane == 0) { redp[wave][1 + 2 * k] = pa; redp[wave][2 + 2 * k] = pb; }
    }
    __syncthreads();

    if (wave == 0) {                       // Einstein midpoint + k2p + lift
      float denom = redp[0][0] + redp[1][0] + redp[2][0] + redp[3][0];
      float num = redp[0][lane + 1] + redp[1][lane + 1] + redp[2][lane + 1] + redp[3][lane + 1];
      float mid = num / denom;             // Klein coords
      float kl = mid * mid;
#pragma unroll
      for (int d = 1; d < 64; d <<= 1) kl += __shfl_xor(kl, d);
      float u = sqrtf(fmaxf(1.f - kl, 1e-12f));
      float pc = mid / (1.f + u);
      float sp = kl / ((1.f + u) * (1.f + u));
      float dd = fmaxf(1.f - sp, 1e-12f);
      qh[lane + 1] = 2.f * pc / dd;
      if (lane == 0) qh[0] = (1.f + sp) / dd;
    }
    __syncthreads();
  }
  if (tid < 65) qh_out[(size_t)bh * 65 + tid] = qh[tid];
}

// ---------------------------------------------------------------------------
// label distances + aggregation MLP (unchanged from R5)
__global__ __launch_bounds__(256) void label_mlp(
    const float* __restrict__ qh, const u16* __restrict__ lh,
    const float* __restrict__ w1, const float* __restrict__ b1,
    const float* __restrict__ w2, const float* __restrict__ b2,
    const float* __restrict__ w3, const float* __restrict__ b3,
    const float* __restrict__ w4, const float* __restrict__ b4,
    const int* __restrict__ mask_label, float* __restrict__ out) {
  int blk = blockIdx.x;
  int b = blk >> 5, lb = blk & 31;
  int l = lb * 256 + threadIdx.x;
  const float* qb = qh + (size_t)b * 1040;

  float inner[16];
  float l0 = bf2f(lh[l]);
#pragma unroll
  for (int h = 0; h < 16; h++) inner[h] = -qb[h * 65] * l0;
  for (int c = 1; c < 65; c++) {
    float lc = bf2f(lh[(size_t)c * 8192 + l]);
#pragma unroll
    for (int h = 0; h < 16; h++) inner[h] = fmaf(qb[h * 65 + c], lc, inner[h]);
  }
  float d[16];
#pragma unroll
  for (int h = 0; h < 16; h++) d[h] = acoshf(fmaxf(-inner[h], 1.f + 1e-6f));

  float x1[32];
#pragma unroll
  for (int o = 0; o < 32; o++) {
    float a = b1[o];
#pragma unroll
    for (int h = 0; h < 16; h++) a = fmaf(d[h], w1[h * 32 + o], a);
    x1[o] = fmaxf(a, 0.f);
  }
  float x2[32];
#pragma unroll
  for (int o = 0; o < 32; o++) {
    float a = b2[o];
#pragma unroll
    for (int i = 0; i < 32; i++) a = fmaf(x1[i], w2[i * 32 + o], a);
    x2[o] = fmaxf(a, 0.f);
  }
  float x3[16];
#pragma unroll
  for (int o = 0; o < 16; o++) {
    float a = b3[o];
#pragma unroll
    for (int i = 0; i < 32; i++) a = fmaf(x2[i], w3[i * 16 + o], a);
    x3[o] = fmaxf(a, 0.f);
  }
  float acc = b4[0];
#pragma unroll
  for (int h = 0; h < 16; h++) acc = fmaf(x3[h], w4[h], acc);
  out[(size_t)b * 8192 + l] = (mask_label[(size_t)b * 8192 + l] > 0) ? acc : -500.0f;
}

// ---------------------------------------------------------------------------
extern "C" void kernel_launch(void* const* d_in, const int* in_sizes, int n_in,
                              void* d_out, int out_size, void* d_ws, size_t ws_size,
                              hipStream_t stream) {
  const float* e     = (const float*)d_in[0];
  const float* label = (const float*)d_in[1];
  const float* tc_w1 = (const float*)d_in[2];
  const float* tc_b1 = (const float*)d_in[3];
  const float* tc_w2 = (const float*)d_in[4];
  const float* tc_b2 = (const float*)d_in[5];
  const float* hyp_w = (const float*)d_in[6];
  const float* hyp_b = (const float*)d_in[7];
  const float* aw1 = (const float*)d_in[8];
  const float* ab1 = (const float*)d_in[9];
  const float* aw2 = (const float*)d_in[10];
  const float* ab2 = (const float*)d_in[11];
  const float* aw3 = (const float*)d_in[12];
  const float* ab3 = (const float*)d_in[13];
  const float* aw4 = (const float*)d_in[14];
  const float* ab4 = (const float*)d_in[15];
  const int* y          = (const int*)d_in[16];
  const int* mask_text  = (const int*)d_in[17];
  const int* mask_label = (const int*)d_in[18];
  float* out = (float*)d_out;

  char* ws = (char*)d_ws;
  // [0, 67.1MB): X8 (fp8 32768x2048); qh (133KB) aliases it after gemm2
  // [67.1MB, 135.3MB): kh bf16 [512][65][1024]
  // [135.3MB, 168.8MB): e8 fp8 [32768][1024]
  u8*    X8    = (u8*)(ws + 0);
  float* qh    = (float*)(ws + 0);
  u16*   kh    = (u16*)(ws + 67108864ull);
  u8*    e8    = (u8*)(ws + 135266304ull);
  u8*    w1T8  = (u8*)(ws + 168820736ull);
  u8*    w2eT8 = (u8*)(ws + 170917888ull);
  float* beff  = (float*)(ws + 173015040ull);
  u16*   lh    = (u16*)(ws + 173019136ull);   // bf16 [65][8192] = 1.06MB

  prep_kernel<<<673 + 8192, 256, 0, stream>>>(e, tc_w1, tc_w2, tc_b2, hyp_w, hyp_b,
                                              label, e8, w1T8, w2eT8, beff, lh);
  // scale B bytes (E8M0, replicated): 0x7A = 2^-5 (cancels w1 x32),
  // 0x79 = 2^-6 (cancels w2eff x64)
  gemm_mx<0><<<4096, 256, 0, stream>>>(e8, w1T8, tc_b1, X8, nullptr, 2048, 1024,
                                       0x7A7A7A7Au);
  gemm_mx<1><<<2048, 256, 0, stream>>>(X8, w2eT8, beff, nullptr, kh, 1024, 2048,
                                       0x79797979u);
  attn_kernel<<<512, 256, 0, stream>>>(kh, label, y, mask_text, qh);
  label_mlp<<<1024, 256, 0, stream>>>(qh, lh, aw1, ab1, aw2, ab2, aw3, ab3, aw4, ab4,
                                      mask_label, out);
}